// Round 9
// baseline (118.272 us; speedup 1.0000x reference)
//
#include <hip/hip_runtime.h>

#define Bn 16
#define Hn 128
#define Wn 8192
#define NMAX 64

typedef float nt_f4 __attribute__((ext_vector_type(4)));              // native vec for nontemporal builtin
typedef float f2a8 __attribute__((ext_vector_type(2), aligned(8)));   // 8B-aligned float2 load

// =====================================================================
// Fused row compaction, LDS-packed, pair-load edition. One block per
// row (2048 blocks, 256 threads = 4 waves).
//  - wave 0: 64-lane width scan; row&127==0 blocks emit xi_new (f32).
//  - PASS 1: per segment one predicated 8B-aligned float2 load per lane
//    (16 VMEM instrs/thread vs 32 scalar; reads only used cols ~25 MB).
//  - PASS 2: scatter pairs into LDS row image; lane 0 drops sep token.
//  - FINAL: 8 NT float4 stores/thread; groups past the packed tail
//    store register zeros (no LDS traffic for the ~57% zero tail).
// =====================================================================
__global__ __launch_bounds__(256) void row_pack_lds_kernel(
    const float* __restrict__ x, const int* __restrict__ xi,
    const int* __restrict__ N, const float* __restrict__ sep_param,
    float* __restrict__ out, float* __restrict__ out_xi) {
    __shared__ float s_row[Wn];          // 32 KB row image
    __shared__ int s_start[NMAX];
    __shared__ int s_w[NMAX];
    __shared__ int s_src0[NMAX];
    __shared__ int s_n, s_tail, s_wide;

    const int row = blockIdx.x;          // b*H + h  (C==1)
    const int b   = row >> 7;
    const int tid = threadIdx.x;

    if (tid < NMAX) {                    // wave 0: 64-lane width scan
        int nb = N[b];
        int s0 = xi[(b * NMAX + tid) * 2 + 0];
        int s1 = xi[(b * NMAX + tid) * 2 + 1];
        int w = s1 - s0; if (w < 0) w = 0;
        bool valid = tid < nb;
        int wv = valid ? w : 0;
        int c = wv;
        #pragma unroll
        for (int d = 1; d < 64; d <<= 1) {
            int t = __shfl_up(c, d, 64);
            if (tid >= d) c += t;
        }
        int start_new = c - wv + tid;
        int end_new   = c + tid;
        s_start[tid] = start_new;
        s_w[tid]     = wv;
        s_src0[tid]  = s0;
        // wide iff fast path (pair loads, 128 dwords from aligned base)
        // can't cover the segment: w + (src0&1) > 128
        unsigned long long wide = __ballot((wv + (s0 & 1)) > 128);
        if (tid == 0) {
            s_n = nb;
            s_wide = (wide != 0ULL) ? 1 : 0;
        }
        int last = (nb > 0) ? (nb - 1) : 0;
        if (tid == last) s_tail = (nb > 0) ? end_new : 0;
        if ((row & 127) == 0) {          // fused xi_new (16 writer blocks)
            out_xi[(b * NMAX + tid) * 2 + 0] = valid ? (float)start_new : 0.0f;
            out_xi[(b * NMAX + tid) * 2 + 1] = valid ? (float)end_new : 0.0f;
        }
    }
    __syncthreads();

    const int nb   = s_n;
    const int tail = s_tail;
    const float sep = sep_param[0];
    const float* __restrict__ xrow = x + (size_t)row * Wn;
    float* __restrict__ orow = out + (size_t)row * Wn;
    const int wave = tid >> 6;
    const int lane = tid & 63;

    // ---- PASS 1: all pair loads (independent, predicated) ----
    f2a8 pv[16];
    int sg_s[16], sg_w[16], sg_off[16], sg_sep[16];
    #pragma unroll
    for (int k = 0; k < 16; ++k) {
        const int seg = wave + 4 * k;
        const bool act = seg < nb;
        const int s    = act ? s_start[seg] : 0;
        const int w    = act ? s_w[seg] : 0;
        const int src0 = act ? s_src0[seg] : 0;
        const int off  = src0 & 1;
        sg_s[k]   = s;
        sg_w[k]   = w;
        sg_off[k] = off;
        sg_sep[k] = (act && seg < nb - 1) ? 1 : 0;
        f2a8 p = {0.0f, 0.0f};
        if (act && (2 * lane < off + w)) {
            p = *reinterpret_cast<const f2a8*>(xrow + (src0 - off) + 2 * lane);
        }
        pv[k] = p;
    }

    // ---- PASS 2: scatter pairs into LDS + sep tokens ----
    #pragma unroll
    for (int k = 0; k < 16; ++k) {
        const int s  = sg_s[k];
        const int w  = sg_w[k];
        const int p0 = 2 * lane - sg_off[k];     // p0 >= -1
        if (p0 >= 0 && p0 < w)  s_row[s + p0]     = pv[k].x;
        if (p0 + 1 < w)         s_row[s + p0 + 1] = pv[k].y;
        if (lane == 0 && sg_sep[k]) s_row[s + w]  = sep;
    }

    // ---- rare fallback for segments wider than the pair window ----
    if (s_wide) {
        for (int seg = wave; seg < nb; seg += 4) {
            const int w    = s_w[seg];
            const int src0 = s_src0[seg];
            const int off  = src0 & 1;
            for (int p = 128 - off + lane; p < w; p += 64) {
                s_row[s_start[seg] + p] = xrow[src0 + p];
            }
        }
    }

    // ---- zero LDS only up to 16B alignment of the tail (<=3 elems) ----
    const int t4 = (tail + 3) & ~3;
    if (tid < (t4 - tail)) s_row[tail + tid] = 0.0f;
    __syncthreads();

    // ---- FINAL: NT float4 row store; zero groups bypass LDS ----
    const float4* s_row4 = reinterpret_cast<const float4*>(s_row);
    nt_f4* orow4 = reinterpret_cast<nt_f4*>(orow);
    #pragma unroll
    for (int g = 0; g < 8; ++g) {
        const int idx = g * 256 + tid;
        nt_f4 v = {0.0f, 0.0f, 0.0f, 0.0f};
        if (idx * 4 < t4) {                      // t4, idx*4 both 4-aligned: no straddle
            float4 t = s_row4[idx];
            v.x = t.x; v.y = t.y; v.z = t.z; v.w = t.w;
        }
        __builtin_nontemporal_store(v, orow4 + idx);
    }
}

extern "C" void kernel_launch(void* const* d_in, const int* in_sizes, int n_in,
                              void* d_out, int out_size, void* d_ws, size_t ws_size,
                              hipStream_t stream) {
    const float* x   = (const float*)d_in[0];
    const int* xi    = (const int*)d_in[1];
    const int* N     = (const int*)d_in[2];
    const float* sep = (const float*)d_in[3];

    float* out_x  = (float*)d_out;
    float* out_xi = (float*)d_out + (size_t)Bn * Hn * Wn;

    row_pack_lds_kernel<<<Bn * Hn, 256, 0, stream>>>(x, xi, N, sep, out_x, out_xi);
}

// Round 10
// 114.520 us; speedup vs baseline: 1.0328x; 1.0328x over previous
//
#include <hip/hip_runtime.h>

#define Bn 16
#define Hn 128
#define Wn 8192
#define NMAX 64

typedef float nt_f4 __attribute__((ext_vector_type(4)));  // native vec for nontemporal builtin

// =====================================================================
// Fused row compaction, LDS-packed (R8 — best known: 115.4 us).
// One block per row (2048 blocks, 256 threads = 4 waves).
//  - wave 0: 64-lane width scan; blocks with (row&127)==0 also emit
//    xi_new (as float32) -> no separate xi kernel.
//  - PASS 1: all 32 predicated global loads per thread into registers
//    (full MLP, reads ONLY used columns ~25 MB).
//  - PASS 2: scatter into LDS row image (64-lane contiguous runs ->
//    2-way bank aliasing, free) + sep tokens; zero LDS tail.
//  - FINAL: 8 aligned nontemporal float4 stores/thread.
// R9 post-mortem: pair-load (f2) PASS 1 + tail-bypass stores regressed
// +2.9 us (VGPR pressure + divergent store branch) — load-issue is NOT
// the binding constraint; do not re-attempt.
// =====================================================================
__global__ __launch_bounds__(256) void row_pack_lds_kernel(
    const float* __restrict__ x, const int* __restrict__ xi,
    const int* __restrict__ N, const float* __restrict__ sep_param,
    float* __restrict__ out, float* __restrict__ out_xi) {
    __shared__ float s_row[Wn];          // 32 KB row image
    __shared__ int s_start[NMAX];
    __shared__ int s_w[NMAX];
    __shared__ int s_src0[NMAX];
    __shared__ int s_n, s_tail, s_wide;

    const int row = blockIdx.x;          // b*H + h  (C==1)
    const int b   = row >> 7;
    const int tid = threadIdx.x;

    if (tid < NMAX) {                    // wave 0: 64-lane width scan
        int nb = N[b];
        int s0 = xi[(b * NMAX + tid) * 2 + 0];
        int s1 = xi[(b * NMAX + tid) * 2 + 1];
        int w = s1 - s0; if (w < 0) w = 0;
        bool valid = tid < nb;
        int wv = valid ? w : 0;
        int c = wv;
        #pragma unroll
        for (int d = 1; d < 64; d <<= 1) {
            int t = __shfl_up(c, d, 64);
            if (tid >= d) c += t;
        }
        int start_new = c - wv + tid;
        int end_new   = c + tid;
        s_start[tid] = start_new;
        s_w[tid]     = wv;
        s_src0[tid]  = s0;
        unsigned long long wide = __ballot(wv > 127);
        if (tid == 0) {
            s_n = nb;
            s_wide = (wide != 0ULL) ? 1 : 0;
        }
        int last = (nb > 0) ? (nb - 1) : 0;
        if (tid == last) s_tail = (nb > 0) ? end_new : 0;
        if ((row & 127) == 0) {          // fused xi_new (16 writer blocks)
            out_xi[(b * NMAX + tid) * 2 + 0] = valid ? (float)start_new : 0.0f;
            out_xi[(b * NMAX + tid) * 2 + 1] = valid ? (float)end_new : 0.0f;
        }
    }
    __syncthreads();

    const int nb   = s_n;
    const int tail = s_tail;
    const float sep = sep_param[0];
    const float* __restrict__ xrow = x + (size_t)row * Wn;
    float* __restrict__ orow = out + (size_t)row * Wn;
    const int wave = tid >> 6;
    const int lane = tid & 63;

    // ---- PASS 1: issue ALL global loads (independent, predicated) ----
    float v0[16], v1[16];
    int sg_s[16], sg_wt[16];
    #pragma unroll
    for (int k = 0; k < 16; ++k) {
        const int seg = wave + 4 * k;
        const bool act = seg < nb;
        const int s    = act ? s_start[seg] : 0;
        const int w    = act ? s_w[seg] : 0;
        const int src0 = act ? s_src0[seg] : 0;
        sg_s[k]  = s;
        sg_wt[k] = act ? (w + ((seg < nb - 1) ? 1 : 0)) : 0;
        v0[k] = (lane < w)      ? xrow[src0 + lane]      : sep;
        v1[k] = (lane + 64 < w) ? xrow[src0 + lane + 64] : sep;
    }

    // ---- PASS 2: scatter into LDS row image (2-way aliasing = free) ----
    #pragma unroll
    for (int k = 0; k < 16; ++k) {
        if (lane < sg_wt[k])      s_row[sg_s[k] + lane]      = v0[k];
        if (lane + 64 < sg_wt[k]) s_row[sg_s[k] + lane + 64] = v1[k];
    }

    // ---- rare fallback for segments wider than 128 (never in practice) ----
    if (s_wide) {
        for (int seg = wave; seg < nb; seg += 4) {
            const int w = s_w[seg];
            const int wtot = w + ((seg < nb - 1) ? 1 : 0);
            for (int l = 128 + lane; l < wtot; l += 64) {
                s_row[s_start[seg] + l] = (l < w) ? xrow[s_src0[seg] + l] : sep;
            }
        }
    }

    // ---- zero LDS tail [tail, Wn): scalar to 16B alignment, then b128 ----
    const int t4 = (tail + 3) & ~3;
    if (tid < (t4 - tail)) s_row[tail + tid] = 0.0f;    // <=3 threads
    float4* s_row4 = reinterpret_cast<float4*>(s_row);
    const float4 z4 = make_float4(0.0f, 0.0f, 0.0f, 0.0f);
    for (int i4 = (t4 >> 2) + tid; i4 < (Wn >> 2); i4 += 256) {
        s_row4[i4] = z4;
    }
    __syncthreads();

    // ---- FINAL: aligned nontemporal float4 row store ----
    nt_f4* orow4 = reinterpret_cast<nt_f4*>(orow);
    #pragma unroll
    for (int g = 0; g < 8; ++g) {
        float4 t = s_row4[g * 256 + tid];
        nt_f4 v = {t.x, t.y, t.z, t.w};
        __builtin_nontemporal_store(v, orow4 + g * 256 + tid);
    }
}

extern "C" void kernel_launch(void* const* d_in, const int* in_sizes, int n_in,
                              void* d_out, int out_size, void* d_ws, size_t ws_size,
                              hipStream_t stream) {
    const float* x   = (const float*)d_in[0];
    const int* xi    = (const int*)d_in[1];
    const int* N     = (const int*)d_in[2];
    const float* sep = (const float*)d_in[3];

    float* out_x  = (float*)d_out;
    float* out_xi = (float*)d_out + (size_t)Bn * Hn * Wn;

    row_pack_lds_kernel<<<Bn * Hn, 256, 0, stream>>>(x, xi, N, sep, out_x, out_xi);
}